// Round 1
// baseline (75.866 us; speedup 1.0000x reference)
//
#include <hip/hip_runtime.h>

#define NEG_SLOPE 0.2f
#define EPS 1e-6f

// x: [B=4, C=64, V=3, N=32768] f32, W: [C=64, C=64] f32, out: same as x
// d[b,o,v,n] = sum_i W[o,i] * x[b,i,v,n]
// dot[b,o,n] = sum_v x[b,o,v,n]*d[b,o,v,n]; dnsq = sum_v d^2
// out = dot>=0 ? x : x - (1-slope)*(dot/(dnsq+eps))*d

#define C_CH 64
#define V_DIM 3
#define N_FULL 32768
#define NTILE 64
#define THREADS 256

__global__ __launch_bounds__(THREADS, 2)
void vn_leaky_relu_kernel(const float* __restrict__ x,
                          const float* __restrict__ W,
                          float* __restrict__ out) {
    __shared__ float xs[C_CH * V_DIM][NTILE]; // [i*3+v][n]  48 KB
    __shared__ float Wl[C_CH][C_CH];          // [o][i]      16 KB

    const int t   = threadIdx.x;
    const int blk = blockIdx.x;
    const int b   = blk >> 9;           // / (N_FULL/NTILE) = /512
    const int n0  = (blk & 511) << 6;   // *64

    const float* xb = x + (size_t)b * (C_CH * V_DIM * N_FULL) + n0;

    // ---- stage W: 4096 floats = 1024 float4, coalesced, linear LDS writes
    for (int idx = t; idx < (C_CH * C_CH) / 4; idx += THREADS) {
        float4 w = ((const float4*)W)[idx];
        ((float4*)&Wl[0][0])[idx] = w;
    }
    // ---- stage x tile: 192 rows x 64 floats = 3072 float4, coalesced
    for (int idx = t; idx < (C_CH * V_DIM * NTILE) / 4; idx += THREADS) {
        int row = idx >> 4;           // 0..191  (i*3+v)
        int c4  = idx & 15;
        float4 v = *(const float4*)(xb + (size_t)row * N_FULL + (c4 << 2));
        *(float4*)&xs[row][c4 << 2] = v;
    }
    __syncthreads();

    const int n     = t & 63;        // lane-consecutive n -> conflict-free LDS, coalesced stores
    const int obase = (t >> 6) << 4; // wave-uniform group of 16 output channels

    float acc[16][3];
    #pragma unroll
    for (int oo = 0; oo < 16; ++oo) {
        acc[oo][0] = 0.f; acc[oo][1] = 0.f; acc[oo][2] = 0.f;
    }

    // inner matvec: per i4 step, 12 b32 x-reads (stride-1 across lanes) +
    // 16 b128 W-reads (wave-uniform address -> broadcast, free), 192 FMA
    #pragma unroll 4
    for (int i4 = 0; i4 < C_CH / 4; ++i4) {
        float xv[4][3];
        #pragma unroll
        for (int k = 0; k < 4; ++k) {
            #pragma unroll
            for (int v = 0; v < 3; ++v)
                xv[k][v] = xs[(i4 * 4 + k) * 3 + v][n];
        }
        #pragma unroll
        for (int oo = 0; oo < 16; ++oo) {
            float4 w4 = *(const float4*)&Wl[obase + oo][i4 * 4];
            float wk[4] = {w4.x, w4.y, w4.z, w4.w};
            #pragma unroll
            for (int k = 0; k < 4; ++k) {
                acc[oo][0] = fmaf(wk[k], xv[k][0], acc[oo][0]);
                acc[oo][1] = fmaf(wk[k], xv[k][1], acc[oo][1]);
                acc[oo][2] = fmaf(wk[k], xv[k][2], acc[oo][2]);
            }
        }
    }

    // ---- epilogue: leaky projection + coalesced scalar stores
    float* ob = out + (size_t)b * (C_CH * V_DIM * N_FULL) + n0 + n;
    #pragma unroll
    for (int oo = 0; oo < 16; ++oo) {
        const int o = obase + oo;
        float x0 = xs[o * 3 + 0][n];
        float x1 = xs[o * 3 + 1][n];
        float x2 = xs[o * 3 + 2][n];
        float d0 = acc[oo][0], d1 = acc[oo][1], d2 = acc[oo][2];
        float dot  = x0 * d0 + x1 * d1 + x2 * d2;
        float dnsq = d0 * d0 + d1 * d1 + d2 * d2;
        float f = (1.0f - NEG_SLOPE) * dot / (dnsq + EPS);
        float o0, o1, o2;
        if (dot >= 0.f) {
            o0 = x0; o1 = x1; o2 = x2;
        } else {
            o0 = x0 - f * d0; o1 = x1 - f * d1; o2 = x2 - f * d2;
        }
        float* op = ob + (size_t)o * (V_DIM * N_FULL);
        op[0 * N_FULL] = o0;
        op[1 * N_FULL] = o1;
        op[2 * N_FULL] = o2;
    }
}

extern "C" void kernel_launch(void* const* d_in, const int* in_sizes, int n_in,
                              void* d_out, int out_size, void* d_ws, size_t ws_size,
                              hipStream_t stream) {
    const float* x = (const float*)d_in[0];
    const float* W = (const float*)d_in[1];
    float* out = (float*)d_out;

    const int B = 4;
    const int blocks = B * (N_FULL / NTILE); // 2048
    vn_leaky_relu_kernel<<<blocks, THREADS, 0, stream>>>(x, W, out);
}